// Round 2
// baseline (12009.477 us; speedup 1.0000x reference)
//
#include <hip/hip_runtime.h>

#define B_  64
#define S_  256
#define H_  768
#define H4_ 3072
#define D2_ 1536
#define SEG 64

using u16 = unsigned short;
using u32 = unsigned int;
using u64 = unsigned long long;
typedef __attribute__((ext_vector_type(8))) short bf16x8;
typedef __attribute__((ext_vector_type(4))) float f32x4;
typedef __attribute__((ext_vector_type(4))) unsigned int u32x4;

#define DEV __device__ __forceinline__

DEV float bf2f(u16 u){ union{u32 i; float f;} c; c.i = ((u32)u)<<16; return c.f; }
DEV u16 f2bf(float f){ union{float f; u32 i;} c; c.f = f; return (u16)((c.i + 0x7FFFu + ((c.i>>16)&1u)) >> 16); }
DEV float sigm(float x){ return 1.f/(1.f + __expf(-x)); }
DEV float tanh_(float x){ return 2.f/(1.f + __expf(-2.f*x)) - 1.f; }

// device-scope (agent) coherent ops: bypass stale per-XCD L2 without full fences
DEV u64 aload64(const u16* p){ return __hip_atomic_load((u64*)p, __ATOMIC_RELAXED, __HIP_MEMORY_SCOPE_AGENT); }
DEV void astore64(u16* p, u64 v){ __hip_atomic_store((u64*)p, v, __ATOMIC_RELAXED, __HIP_MEMORY_SCOPE_AGENT); }
DEV void astore32(u16* p, u32 v){ __hip_atomic_store((u32*)p, v, __ATOMIC_RELAXED, __HIP_MEMORY_SCOPE_AGENT); }

DEV f32x4 mfma16(bf16x8 a, bf16x8 b, f32x4 c){
  return __builtin_amdgcn_mfma_f32_16x16x32_bf16(a, b, c, 0, 0, 0);
}

// flag-array grid barrier; release store + relaxed poll. Data exchange uses
// coherent atomics, so no acquire fence (keeps weights resident in L2).
DEV void gbar(int* flags, int slot_me, int slot_base, int n, int ep){
  __threadfence_block();            // drain this thread's stores (vmcnt)
  __syncthreads();
  if (threadIdx.x == 0)
    __hip_atomic_store(&flags[slot_me*32], ep, __ATOMIC_RELEASE, __HIP_MEMORY_SCOPE_AGENT);
  if ((int)threadIdx.x < n) {
    while (__hip_atomic_load(&flags[(slot_base + (int)threadIdx.x)*32], __ATOMIC_RELAXED, __HIP_MEMORY_SCOPE_AGENT) < ep) {}
  }
  __syncthreads();
}

// ---------------- fp32 -> bf16 convert (strided dst for packing) ---------------
__global__ void k_conv(const float* __restrict__ src, u16* __restrict__ dst,
                       int cols, int sld, int dld){
  const long r = blockIdx.x;
  for (int c = threadIdx.x*4; c < cols; c += 1024) {
    const float* sp = src + r*sld + c;
    float a = sp[0], b = sp[1], cc = sp[2], d = sp[3];
    u64 pack = (u64)f2bf(a) | ((u64)f2bf(b)<<16) | ((u64)f2bf(cc)<<32) | ((u64)f2bf(d)<<48);
    *(u64*)(dst + r*dld + c) = pack;
  }
}

// ---- C(bf16, 4096x3072) = A[b,t0+tt](bf16) @ W(bf16)^T + bias, 128x128 tile ---
// A rows selected as (b = fr>>6)*S_ + t0 + (fr&63); C rows contiguous (b*64+tt).
__global__ __launch_bounds__(256) void k_gemm(
    const u16* __restrict__ A, const u16* __restrict__ W,
    const float* __restrict__ bias, u16* __restrict__ C, int K, int t0)
{
  __shared__ u16 at[128*40];
  __shared__ u16 bt[128*40];
  const int tid = threadIdx.x;
  const int L = tid & 63, wv = tid >> 6;
  const int mq = wv >> 1, nq = wv & 1;
  const int l16 = L & 15, quad = L >> 4;
  const long mb = blockIdx.y, nb = blockIdx.x;

  f32x4 acc[4][4];
  #pragma unroll
  for (int m=0;m<4;++m)
    #pragma unroll
    for (int n=0;n<4;++n)
      acc[m][n] = (f32x4){0.f,0.f,0.f,0.f};

  const int r = tid >> 1, c0 = (tid & 1) * 16;
  const int fr = (int)mb*128 + r;
  const long arow = ((long)(fr >> 6))*S_ + t0 + (fr & 63);
  const u16* Arow = A + arow*(long)K + c0;
  const u16* Wrow = W + (nb*128 + r)*(long)K + c0;

  for (int kb = 0; kb < K; kb += 32) {
    *(u32x4*)&at[r*40 + c0]     = *(const u32x4*)(Arow + kb);
    *(u32x4*)&at[r*40 + c0 + 8] = *(const u32x4*)(Arow + kb + 8);
    *(u32x4*)&bt[r*40 + c0]     = *(const u32x4*)(Wrow + kb);
    *(u32x4*)&bt[r*40 + c0 + 8] = *(const u32x4*)(Wrow + kb + 8);
    __syncthreads();
    bf16x8 af[4], bfr[4];
    #pragma unroll
    for (int m=0;m<4;++m) af[m]  = *(const bf16x8*)&at[(mq*64 + m*16 + l16)*40 + quad*8];
    #pragma unroll
    for (int n=0;n<4;++n) bfr[n] = *(const bf16x8*)&bt[(nq*64 + n*16 + l16)*40 + quad*8];
    #pragma unroll
    for (int m=0;m<4;++m)
      #pragma unroll
      for (int n=0;n<4;++n)
        acc[m][n] = mfma16(af[m], bfr[n], acc[m][n]);
    __syncthreads();
  }
  #pragma unroll
  for (int n=0;n<4;++n) {
    const long col = nb*128 + nq*64 + n*16 + l16;
    const float bv = bias[col];
    #pragma unroll
    for (int m=0;m<4;++m) {
      const long row0 = mb*128 + mq*64 + m*16 + quad*4;
      #pragma unroll
      for (int rr=0;rr<4;++rr)
        C[(row0+rr)*3072 + col] = f2bf(acc[m][n][rr] + bv);
    }
  }
}

// ---------------- persistent bilstm segment: 96 wgs = 2 dirs x 48 slices -------
__global__ __launch_bounds__(256) void k_bilstm(
    const u16* __restrict__ Gf, const u16* __restrict__ Gb,
    const u16* __restrict__ Whhf, const u16* __restrict__ Whhb,
    const u16* __restrict__ h0, u16* __restrict__ lstm,
    float* __restrict__ cstf, float* __restrict__ cstb,
    int* __restrict__ flags, int t0f, int tb0, int ep0)
{
  __shared__ u16 lds[64*392];          // staged h chunk (64 x 384, pad 8); aliased gbuf
  float* gbuf = (float*)lds;           // [4][64][16] fp32 = 16 KB
  const int wg = blockIdx.x;
  const int dir = wg / 48, s = wg % 48;
  const int tid = threadIdx.x, q = tid>>6, L = tid&63, l16 = L&15, quad = L>>4;

  const u16* Gsrc = dir ? Gb : Gf;
  const u16* W = dir ? Whhb : Whhf;
  float* cst = dir ? cstb : cstf;

  // persistent B fragments: this wave's gate rows (16 dims x 768 K) in VGPRs
  bf16x8 bfr[24];
  {
    const u16* wr = W + (long)(q*H_ + s*16 + l16)*H_;
    #pragma unroll
    for (int kk=0;kk<24;++kk) bfr[kk] = *(const bf16x8*)(wr + kk*32 + quad*8);
  }

  const int cb = tid>>2, cdl = (tid&3)*4;   // combine: batch, dim-base (4 dims)
  float creg[4];
  #pragma unroll
  for (int i=0;i<4;++i) creg[i] = cst[cb*H_ + s*16 + cdl + i];
  const int sr = tid>>2, sl = tid&3;        // staging row / lane-in-row

  for (int t=0; t<SEG; ++t) {
    const int tp = dir ? (tb0 + SEG-1 - t) : (t0f + t);
    const u16* hbase; long ldh;
    const bool first = dir ? (tp == S_-1) : (tp == 0);
    if (first) { hbase = h0 + dir*H_; ldh = D2_; }
    else {
      const int tprev = dir ? (tp+1) : (tp-1);
      hbase = lstm + (long)tprev*D2_ + dir*H_;
      ldh = (long)S_*D2_;
    }
    f32x4 acc[4];
    #pragma unroll
    for (int m=0;m<4;++m) acc[m] = (f32x4){0.f,0.f,0.f,0.f};

    #pragma unroll
    for (int ch=0; ch<2; ++ch) {
      __syncthreads();
      const u16* srow = hbase + (long)sr*ldh + ch*384;
      #pragma unroll
      for (int jj=0; jj<24; ++jj) {
        const int cu = (sl + jj*4) * 4;
        *(u64*)&lds[sr*392 + cu] = aload64(srow + cu);
      }
      __syncthreads();
      #pragma unroll
      for (int kk=0; kk<12; ++kk) {
        #pragma unroll
        for (int m=0;m<4;++m) {
          bf16x8 a = *(const bf16x8*)&lds[(m*16 + l16)*392 + kk*32 + quad*8];
          acc[m] = mfma16(a, bfr[ch*12 + kk], acc[m]);
        }
      }
    }
    __syncthreads();
    #pragma unroll
    for (int m=0;m<4;++m)
      #pragma unroll
      for (int rr=0;rr<4;++rr)
        gbuf[q*1024 + (m*16 + quad*4 + rr)*16 + l16] = acc[m][rr];
    __syncthreads();
    {
      const int gidx = cb*SEG + (dir ? (tp - tb0) : (tp - t0f));
      const u16* grow = Gsrc + (long)gidx*H4_ + s*16 + cdl;
      float gv[4][4];
      #pragma unroll
      for (int qq=0; qq<4; ++qq)
        #pragma unroll
        for (int i=0;i<4;++i)
          gv[qq][i] = gbuf[qq*1024 + cb*16 + cdl + i] + bf2f(grow[qq*H_ + i]);
      u64 hp = 0;
      #pragma unroll
      for (int i=0;i<4;++i) {
        const float c = sigm(gv[1][i])*creg[i] + sigm(gv[0][i])*tanh_(gv[2][i]);
        creg[i] = c;
        const float h = sigm(gv[3][i])*tanh_(c);
        hp |= ((u64)f2bf(h)) << (16*i);
      }
      astore64(lstm + ((long)cb*S_ + tp)*D2_ + dir*H_ + s*16 + cdl, hp);
    }
    gbar(flags, wg, dir*48, 48, ep0 + t + 1);   // per-direction barrier group
  }
  #pragma unroll
  for (int i=0;i<4;++i) cst[cb*H_ + s*16 + cdl + i] = creg[i];
}

// ---------------- persistent decode segment: 96 wgs = 48 slices x 2 halves -----
__global__ __launch_bounds__(256) void k_decode(
    const u16* __restrict__ Gsub, const u16* __restrict__ Wsub,
    const u16* __restrict__ Wwrd, const float* __restrict__ wbias,
    const float* __restrict__ clsW, const int* __restrict__ golds,
    u16* __restrict__ Sh0, u16* __restrict__ Sh1,
    u16* __restrict__ U0, u16* __restrict__ U1,
    float* __restrict__ scS, float* __restrict__ wcS, float* __restrict__ whS,
    float* __restrict__ partials, int* __restrict__ flags,
    int t0, int nsteps, int ep0)
{
  __shared__ u16 lds[32*776];          // staged A chunk (32 x 768, pad 8); aliased gbuf
  float* gbuf = (float*)lds;           // [4][32][16] fp32 = 8 KB
  const int wg = blockIdx.x;
  const int s = wg >> 1, mh = wg & 1;
  const int tid = threadIdx.x, q = tid>>6, L = tid&63, l16 = L&15, quad = L>>4;

  const u16* Bsub = Wsub + (long)(q*H_ + s*16 + l16)*H_;
  const u16* Bwrd = Wwrd + (long)(q*H_ + s*16 + l16)*2304;

  const int sr = tid>>3, sl = tid&7;        // staging: 32 rows, 8 threads/row
  const int cbl = tid>>3, cdl = (tid&7)*2;  // combine: local batch, dim pair
  const int cbg = mh*32 + cbl;
  const int col = s*16 + cdl;

  float screg[2], wcreg[2], whreg[2];
  #pragma unroll
  for (int i=0;i<2;++i){
    screg[i] = scS[cbg*H_ + col + i];
    wcreg[i] = wcS[cbg*H_ + col + i];
    whreg[i] = whS[cbg*H_ + col + i];
  }

  for (int tt=0; tt<nsteps; ++tt) {
    const int t = t0 + tt;
    u16* ShR = (t&1) ? Sh1 : Sh0;
    u16* ShW = (t&1) ? Sh0 : Sh1;
    u16* UR  = (t&1) ? U1 : U0;
    u16* UW  = (t&1) ? U0 : U1;
    const int gld = golds[cbg*S_ + t + 1];
    const bool keep = (gld == 0);

    // ---- phase 1: subword cell (K=768) ----
    f32x4 acc[2];
    acc[0] = (f32x4){0.f,0.f,0.f,0.f}; acc[1] = acc[0];
    __syncthreads();
    {
      const u16* srow = ShR + (long)(mh*32 + sr)*H_;
      #pragma unroll
      for (int jj=0;jj<24;++jj){
        const int cu = (sl + jj*8)*4;
        *(u64*)&lds[sr*776 + cu] = aload64(srow + cu);
      }
    }
    __syncthreads();
    #pragma unroll
    for (int kk=0;kk<24;++kk){
      const bf16x8 bw = *(const bf16x8*)(Bsub + kk*32 + quad*8);
      #pragma unroll
      for (int m=0;m<2;++m){
        bf16x8 a = *(const bf16x8*)&lds[(m*16+l16)*776 + kk*32 + quad*8];
        acc[m] = mfma16(a, bw, acc[m]);
      }
    }
    __syncthreads();
    #pragma unroll
    for (int m=0;m<2;++m)
      #pragma unroll
      for (int rr=0;rr<4;++rr)
        gbuf[q*512 + (m*16+quad*4+rr)*16 + l16] = acc[m][rr];
    __syncthreads();
    {
      const u16* grow = Gsub + ((long)cbg*SEG + tt)*H4_ + col;
      u32 hp=0, cp=0;
      #pragma unroll
      for (int i=0;i<2;++i){
        const float gi = gbuf[0*512 + cbl*16 + cdl+i] + bf2f(grow[0*H_ + i]);
        const float gf = gbuf[1*512 + cbl*16 + cdl+i] + bf2f(grow[1*H_ + i]);
        const float gg = gbuf[2*512 + cbl*16 + cdl+i] + bf2f(grow[2*H_ + i]);
        const float go = gbuf[3*512 + cbl*16 + cdl+i] + bf2f(grow[3*H_ + i]);
        const float c1 = sigm(gf)*screg[i] + sigm(gi)*tanh_(gg);
        const float h1 = sigm(go)*tanh_(c1);
        screg[i] = keep ? c1 : 0.f;
        hp |= ((u32)f2bf(h1)) << (16*i);
        cp |= ((u32)f2bf(c1)) << (16*i);
      }
      astore32(UR + (long)cbg*2304 + col, hp);         // subword = [h1 | c1]
      astore32(UR + (long)cbg*2304 + H_ + col, cp);
      astore32(ShW + (long)cbg*H_ + col, keep ? hp : 0u);
    }
    gbar(flags, wg, 0, 96, ep0 + 2*tt + 1);

    // ---- phase 2: word cell (K=2304 over [h1|c1|Wh]) ----
    acc[0] = (f32x4){0.f,0.f,0.f,0.f}; acc[1] = acc[0];
    for (int ch=0; ch<3; ++ch){
      __syncthreads();
      {
        const u16* srow = UR + (long)(mh*32 + sr)*2304 + ch*768;
        #pragma unroll
        for (int jj=0;jj<24;++jj){
          const int cu = (sl + jj*8)*4;
          *(u64*)&lds[sr*776 + cu] = aload64(srow + cu);
        }
      }
      __syncthreads();
      #pragma unroll
      for (int kk=0;kk<24;++kk){
        const bf16x8 bw = *(const bf16x8*)(Bwrd + ch*768 + kk*32 + quad*8);
        #pragma unroll
        for (int m=0;m<2;++m){
          bf16x8 a = *(const bf16x8*)&lds[(m*16+l16)*776 + kk*32 + quad*8];
          acc[m] = mfma16(a, bw, acc[m]);
        }
      }
    }
    __syncthreads();
    #pragma unroll
    for (int m=0;m<2;++m)
      #pragma unroll
      for (int rr=0;rr<4;++rr)
        gbuf[q*512 + (m*16+quad*4+rr)*16 + l16] = acc[m][rr];
    __syncthreads();
    {
      float p0 = 0.f, p1 = 0.f;
      u32 wp = 0;
      #pragma unroll
      for (int i=0;i<2;++i){
        const float gi = gbuf[0*512 + cbl*16 + cdl+i] + wbias[0*H_ + col+i];
        const float gf = gbuf[1*512 + cbl*16 + cdl+i] + wbias[1*H_ + col+i];
        const float gg = gbuf[2*512 + cbl*16 + cdl+i] + wbias[2*H_ + col+i];
        const float go = gbuf[3*512 + cbl*16 + cdl+i] + wbias[3*H_ + col+i];
        const float wc1 = sigm(gf)*wcreg[i] + sigm(gi)*tanh_(gg);
        const float wh1 = sigm(go)*tanh_(wc1);
        wcreg[i] = keep ? wcreg[i] : wc1;
        whreg[i] = keep ? whreg[i] : wh1;
        p0 += wh1 * clsW[col + i];
        p1 += wh1 * clsW[2304 + col + i];
        wp |= ((u32)f2bf(whreg[i])) << (16*i);
      }
      astore32(UW + (long)cbg*2304 + D2_ + col, wp);   // next step's Wh state
      p0 += __shfl_xor(p0, 1); p0 += __shfl_xor(p0, 2); p0 += __shfl_xor(p0, 4);
      p1 += __shfl_xor(p1, 1); p1 += __shfl_xor(p1, 2); p1 += __shfl_xor(p1, 4);
      if ((tid & 7) == 0){
        float* pp = partials + ((long)(t*48 + s)*64 + cbg)*2;
        pp[0] = p0; pp[1] = p1;
      }
    }
    gbar(flags, wg, 0, 96, ep0 + 2*tt + 2);
  }
  #pragma unroll
  for (int i=0;i<2;++i){
    scS[cbg*H_ + col + i] = screg[i];
    wcS[cbg*H_ + col + i] = wcreg[i];
    whS[cbg*H_ + col + i] = whreg[i];
  }
}

// ---------------- classifier epilogue: out = first | cls_b + wh-part + x-part --
__global__ __launch_bounds__(256) void k_cls(
    const u16* __restrict__ lstm, const float* __restrict__ partials,
    const float* __restrict__ clsW, const float* __restrict__ clsb,
    float* __restrict__ out)
{
  const int ts = blockIdx.x;   // 0..255
  const int b  = blockIdx.y;
  const int tid = threadIdx.x;
  if (ts == 0) {
    if (tid == 0) { out[(long)b*S_*2 + 0] = -1.f; out[(long)b*S_*2 + 1] = 1.f; }
    return;
  }
  const int t = ts - 1;
  float s0 = 0.f, s1 = 0.f;
  const u16* xr = lstm + ((long)b*S_ + ts)*D2_;
  for (int k = tid; k < D2_; k += 256) {
    const float xv = bf2f(xr[k]);
    s0 += xv * clsW[768 + k];
    s1 += xv * clsW[2304 + 768 + k];
  }
  if (tid < 48) {
    const float* pr = partials + ((long)(t*48 + tid)*64 + b)*2;
    s0 += pr[0]; s1 += pr[1];
  }
  __shared__ float r0[256], r1[256];
  r0[tid] = s0; r1[tid] = s1; __syncthreads();
  for (int off = 128; off > 0; off >>= 1) {
    if (tid < off) { r0[tid] += r0[tid+off]; r1[tid] += r1[tid+off]; }
    __syncthreads();
  }
  if (tid == 0) {
    out[((long)b*S_ + ts)*2 + 0] = r0[0] + clsb[0];
    out[((long)b*S_ + ts)*2 + 1] = r1[0] + clsb[1];
  }
}

extern "C" void kernel_launch(void* const* d_in, const int* in_sizes, int n_in,
                              void* d_out, int out_size, void* d_ws, size_t ws_size,
                              hipStream_t stream)
{
  (void)in_sizes; (void)n_in; (void)out_size; (void)ws_size;
  const float* x     = (const float*)d_in[0];
  const int*   golds = (const int*)d_in[1];
  const float* wihf  = (const float*)d_in[2];
  const float* whhf  = (const float*)d_in[3];
  const float* bfw   = (const float*)d_in[4];
  const float* wihb  = (const float*)d_in[5];
  const float* whhb  = (const float*)d_in[6];
  const float* bbw   = (const float*)d_in[7];
  const float* swih  = (const float*)d_in[8];
  const float* swhh  = (const float*)d_in[9];
  const float* sb    = (const float*)d_in[10];
  const float* wwih  = (const float*)d_in[11];
  const float* wwhh  = (const float*)d_in[12];
  const float* wb    = (const float*)d_in[13];
  const float* clsW  = (const float*)d_in[14];
  const float* clsb  = (const float*)d_in[15];
  float* out = (float*)d_out;

  char* base = (char*)d_ws;
  // -------- zero-init region (memset each launch; ws is poisoned 0xAA) --------
  u16*   h0   = (u16*)(base + 0);            // 64x1536 bf16 zeros (196,608 B)
  u16*   Sh0  = (u16*)(base + 196608);       // subword-h state dbuf (98,304 B)
  u16*   Sh1  = (u16*)(base + 295912 - 1000);// = 294912
  u16*   U0   = (u16*)(base + 393216);       // [h1|c1|Wh] dbuf 64x2304 (294,912 B)
  u16*   U1   = (u16*)(base + 688128);
  int*   flg2 = (int*)(base + 983040);       // 96 slots * 128 B
  int*   flg4 = (int*)(base + 995328);
  float* cstf = (float*)(base + 1007616);    // bilstm fwd c-state 64x1536 f32
  float* cstb = (float*)(base + 1400832);
  float* scS  = (float*)(base + 1794048);    // decode subword c 64x768 f32
  float* wcS  = (float*)(base + 1990656);    // decode word c
  float* whS  = (float*)(base + 2187264);    // decode word h
  // zero region ends at 2,383,872
  // -------- scratch (fully written before read) --------------------------------
  u16* xb     = (u16*)(base + 2383872);      // 16384x768 bf16 (25,165,824 B)
  u16* wihf_b = (u16*)(base + 27549696);
  u16* whhf_b = (u16*)(base + 32268288);
  u16* wihb_b = (u16*)(base + 36986880);
  u16* whhb_b = (u16*)(base + 41705472);
  u16* swih_b = (u16*)(base + 46424064);     // 3072x1536
  u16* swhh_b = (u16*)(base + 55861248);     // 3072x768
  u16* wwrd_b = (u16*)(base + 60579840);     // packed [word_Wih | word_Whh] 3072x2304
  u16* Gfseg  = (u16*)(base + 74735616);     // 4096x3072 bf16 seg (25,165,824 B)
  u16* Gbseg  = (u16*)(base + 99901440);     // (prt aliases after bilstm)
  u16* lstm   = (u16*)(base + 125067264);    // (B,S,1536) bf16 (50,331,648 B)
  // total footprint: 175,398,912 B
  u16* Gsubseg = Gfseg;                      // alias: Gf dead after bilstm
  float* prt   = (float*)Gbseg;              // alias: Gb dead after bilstm

  hipMemsetAsync(d_ws, 0, 2383872, stream);

  k_conv<<<16384, 256, 0, stream>>>(x,    xb,     768,  768,  768);
  k_conv<<<3072,  256, 0, stream>>>(wihf, wihf_b, 768,  768,  768);
  k_conv<<<3072,  256, 0, stream>>>(whhf, whhf_b, 768,  768,  768);
  k_conv<<<3072,  256, 0, stream>>>(wihb, wihb_b, 768,  768,  768);
  k_conv<<<3072,  256, 0, stream>>>(whhb, whhb_b, 768,  768,  768);
  k_conv<<<3072,  256, 0, stream>>>(swih, swih_b, 1536, 1536, 1536);
  k_conv<<<3072,  256, 0, stream>>>(swhh, swhh_b, 768,  768,  768);
  k_conv<<<3072,  256, 0, stream>>>(wwih, wwrd_b,        1536, 1536, 2304);
  k_conv<<<3072,  256, 0, stream>>>(wwhh, wwrd_b + 1536, 768,  768,  2304);

  dim3 gg(24, 32);   // 3072 cols x 4096 rows (one 64-step segment, all batches)
  for (int sgi = 0; sgi < 4; ++sgi) {
    const int t0f = sgi*SEG;
    const int tb0 = (3 - sgi)*SEG;
    k_gemm<<<gg, 256, 0, stream>>>(xb, wihf_b, bfw, Gfseg, 768, t0f);
    k_gemm<<<gg, 256, 0, stream>>>(xb, wihb_b, bbw, Gbseg, 768, tb0);
    k_bilstm<<<96, 256, 0, stream>>>(Gfseg, Gbseg, whhf_b, whhb_b, h0, lstm,
                                     cstf, cstb, flg2, t0f, tb0, sgi*SEG);
  }

  for (int sgi = 0; sgi < 4; ++sgi) {
    const int t0 = sgi*SEG;
    const int nsteps = (sgi < 3) ? SEG : (SEG - 1);   // 255 decode steps total
    k_gemm<<<gg, 256, 0, stream>>>(lstm, swih_b, sb, Gsubseg, 1536, t0);
    k_decode<<<96, 256, 0, stream>>>(Gsubseg, swhh_b, wwrd_b, wb, clsW, golds,
                                     Sh0, Sh1, U0, U1, scS, wcS, whS, prt, flg4,
                                     t0, nsteps, 2*SEG*sgi);
  }

  dim3 gc(256, 64);
  k_cls<<<gc, 256, 0, stream>>>(lstm, prt, clsW, clsb, out);
}

// Round 3
// 7450.356 us; speedup vs baseline: 1.6119x; 1.6119x over previous
//
#include <hip/hip_runtime.h>

#define B_  64
#define S_  256
#define H_  768
#define H4_ 3072
#define D2_ 1536
#define SEG 64

using u16 = unsigned short;
using u32 = unsigned int;
using u64 = unsigned long long;
typedef __attribute__((ext_vector_type(8))) short bf16x8;
typedef __attribute__((ext_vector_type(4))) float f32x4;
typedef __attribute__((ext_vector_type(4))) unsigned int u32x4;

#define DEV __device__ __forceinline__

DEV float bf2f(u16 u){ union{u32 i; float f;} c; c.i = ((u32)u)<<16; return c.f; }
DEV u16 f2bf(float f){ union{float f; u32 i;} c; c.f = f; return (u16)((c.i + 0x7FFFu + ((c.i>>16)&1u)) >> 16); }
DEV float sigm(float x){ return 1.f/(1.f + __expf(-x)); }
DEV float tanh_(float x){ return 2.f/(1.f + __expf(-2.f*x)) - 1.f; }

// device-scope (agent) coherent ops: bypass stale per-XCD L2 without full fences
DEV u64 aload64(const u16* p){ return __hip_atomic_load((u64*)p, __ATOMIC_RELAXED, __HIP_MEMORY_SCOPE_AGENT); }
DEV void astore32(u16* p, u32 v){ __hip_atomic_store((u32*)p, v, __ATOMIC_RELAXED, __HIP_MEMORY_SCOPE_AGENT); }

DEV f32x4 mfma16(bf16x8 a, bf16x8 b, f32x4 c){
  return __builtin_amdgcn_mfma_f32_16x16x32_bf16(a, b, c, 0, 0, 0);
}

// flag-array grid barrier; release store + relaxed poll.
DEV void gbar(int* flags, int slot_me, int slot_base, int n, int ep){
  __threadfence_block();
  __syncthreads();
  if (threadIdx.x == 0)
    __hip_atomic_store(&flags[slot_me*32], ep, __ATOMIC_RELEASE, __HIP_MEMORY_SCOPE_AGENT);
  if ((int)threadIdx.x < n) {
    while (__hip_atomic_load(&flags[(slot_base + (int)threadIdx.x)*32], __ATOMIC_RELAXED, __HIP_MEMORY_SCOPE_AGENT) < ep) {}
  }
  __syncthreads();
}

// ---------------- fp32 -> bf16 convert (strided dst for packing) ---------------
__global__ void k_conv(const float* __restrict__ src, u16* __restrict__ dst,
                       int cols, int sld, int dld){
  const long r = blockIdx.x;
  for (int c = threadIdx.x*4; c < cols; c += 1024) {
    const float* sp = src + r*sld + c;
    float a = sp[0], b = sp[1], cc = sp[2], d = sp[3];
    u64 pack = (u64)f2bf(a) | ((u64)f2bf(b)<<16) | ((u64)f2bf(cc)<<32) | ((u64)f2bf(d)<<48);
    *(u64*)(dst + r*dld + c) = pack;
  }
}

// ---- C(bf16, 4096x3072) = A[b,t0+tt](bf16) @ W(bf16)^T + bias, 128x128 tile ---
__global__ __launch_bounds__(256) void k_gemm(
    const u16* __restrict__ A, const u16* __restrict__ W,
    const float* __restrict__ bias, u16* __restrict__ C, int K, int t0)
{
  __shared__ u16 at[128*40];
  __shared__ u16 bt[128*40];
  const int tid = threadIdx.x;
  const int L = tid & 63, wv = tid >> 6;
  const int mq = wv >> 1, nq = wv & 1;
  const int l16 = L & 15, quad = L >> 4;
  const long mb = blockIdx.y, nb = blockIdx.x;

  f32x4 acc[4][4];
  #pragma unroll
  for (int m=0;m<4;++m)
    #pragma unroll
    for (int n=0;n<4;++n)
      acc[m][n] = (f32x4){0.f,0.f,0.f,0.f};

  const int r = tid >> 1, c0 = (tid & 1) * 16;
  const int fr = (int)mb*128 + r;
  const long arow = ((long)(fr >> 6))*S_ + t0 + (fr & 63);
  const u16* Arow = A + arow*(long)K + c0;
  const u16* Wrow = W + (nb*128 + r)*(long)K + c0;

  for (int kb = 0; kb < K; kb += 32) {
    *(u32x4*)&at[r*40 + c0]     = *(const u32x4*)(Arow + kb);
    *(u32x4*)&at[r*40 + c0 + 8] = *(const u32x4*)(Arow + kb + 8);
    *(u32x4*)&bt[r*40 + c0]     = *(const u32x4*)(Wrow + kb);
    *(u32x4*)&bt[r*40 + c0 + 8] = *(const u32x4*)(Wrow + kb + 8);
    __syncthreads();
    bf16x8 af[4], bfr[4];
    #pragma unroll
    for (int m=0;m<4;++m) af[m]  = *(const bf16x8*)&at[(mq*64 + m*16 + l16)*40 + quad*8];
    #pragma unroll
    for (int n=0;n<4;++n) bfr[n] = *(const bf16x8*)&bt[(nq*64 + n*16 + l16)*40 + quad*8];
    #pragma unroll
    for (int m=0;m<4;++m)
      #pragma unroll
      for (int n=0;n<4;++n)
        acc[m][n] = mfma16(af[m], bfr[n], acc[m][n]);
    __syncthreads();
  }
  #pragma unroll
  for (int n=0;n<4;++n) {
    const long col = nb*128 + nq*64 + n*16 + l16;
    const float bv = bias[col];
    #pragma unroll
    for (int m=0;m<4;++m) {
      const long row0 = mb*128 + mq*64 + m*16 + quad*4;
      #pragma unroll
      for (int rr=0;rr<4;++rr)
        C[(row0+rr)*3072 + col] = f2bf(acc[m][n][rr] + bv);
    }
  }
}

// ------- persistent bilstm segment: 192 wgs = 2 dirs x 2 bhalf x 48 slices -----
// 512 thr = 8 waves = gate q(4) x k-half kh(2); weights persistent in VGPRs.
__global__ __launch_bounds__(512,2) void k_bilstm(
    const u16* __restrict__ Gf, const u16* __restrict__ Gb,
    const u16* __restrict__ Whhf, const u16* __restrict__ Whhb,
    const u16* __restrict__ h0, u16* __restrict__ lstm,
    float* __restrict__ cstf, float* __restrict__ cstb,
    int* __restrict__ flags, int t0f, int tb0, int ep0)
{
  __shared__ __align__(16) u16 lds[32*776];  // staged 32x768 h; gbuf aliased
  float* gbuf = (float*)lds;                 // [q][kh][32][16] f32 = 16 KB
  const int wg = blockIdx.x;
  const int dir = wg / 96, rem = wg % 96, mh = rem / 48, s = rem % 48;
  const int tid = threadIdx.x;
  const int wave = tid >> 6, q = wave & 3, kh = wave >> 2;
  const int L = tid & 63, l16 = L & 15, quad = L >> 4;

  const u16* Gsrc = dir ? Gb : Gf;
  const u16* W    = dir ? Whhb : Whhf;
  float* cst      = dir ? cstb : cstf;

  bf16x8 bfr[12];
  {
    const u16* wr = W + (long)(q*H_ + s*16 + l16)*H_ + kh*384 + quad*8;
    #pragma unroll
    for (int kk=0;kk<12;++kk) bfr[kk] = *(const bf16x8*)(wr + kk*32);
  }

  const int lb = tid >> 3, cdl = (tid & 7) * 2;   // valid when tid<256
  const int eb = mh*32 + lb, col = s*16 + cdl;
  const bool ew = (tid < 256);
  float creg[2] = {0.f, 0.f};
  if (ew){ creg[0] = cst[eb*H_ + col]; creg[1] = cst[eb*H_ + col + 1]; }

  const int sr = tid >> 4, sl = tid & 15;

  for (int t=0; t<SEG; ++t) {
    const int tp = dir ? (tb0 + SEG-1 - t) : (t0f + t);
    // prefetch this step's gate values (HBM) before the LLC staging
    u32 g0=0,g1=0,g2=0,g3=0;
    if (ew){
      const int gidx = eb*SEG + (dir ? (tp - tb0) : (tp - t0f));
      const u16* grow = Gsrc + (long)gidx*H4_ + col;
      g0 = *(const u32*)(grow);
      g1 = *(const u32*)(grow + H_);
      g2 = *(const u32*)(grow + 2*H_);
      g3 = *(const u32*)(grow + 3*H_);
    }
    const bool first = dir ? (tp == S_-1) : (tp == 0);
    const u16* hbase; long ldh;
    if (first){ hbase = h0 + dir*H_; ldh = D2_; }
    else {
      const int tprev = dir ? (tp+1) : (tp-1);
      hbase = lstm + (long)tprev*D2_ + dir*H_;
      ldh = (long)S_*D2_;
    }
    {
      const u16* srow = hbase + (long)(mh*32 + sr)*ldh;
      #pragma unroll
      for (int jj=0;jj<12;++jj){
        const int cu = (sl + jj*16)*4;
        *(u64*)&lds[sr*776 + cu] = aload64(srow + cu);
      }
    }
    __syncthreads();
    f32x4 acc[2];
    acc[0] = (f32x4){0.f,0.f,0.f,0.f}; acc[1] = acc[0];
    #pragma unroll
    for (int kk=0;kk<12;++kk)
      #pragma unroll
      for (int m=0;m<2;++m){
        bf16x8 a = *(const bf16x8*)&lds[(m*16+l16)*776 + kh*384 + kk*32 + quad*8];
        acc[m] = mfma16(a, bfr[kk], acc[m]);
      }
    __syncthreads();
    #pragma unroll
    for (int m=0;m<2;++m)
      #pragma unroll
      for (int rr=0;rr<4;++rr)
        gbuf[(q*2+kh)*512 + (m*16+quad*4+rr)*16 + l16] = acc[m][rr];
    __syncthreads();
    if (ew){
      u32 gr[4] = {g0,g1,g2,g3};
      u32 hp = 0;
      #pragma unroll
      for (int i=0;i<2;++i){
        float gv[4];
        #pragma unroll
        for (int qq=0;qq<4;++qq)
          gv[qq] = gbuf[(qq*2+0)*512 + lb*16 + cdl+i]
                 + gbuf[(qq*2+1)*512 + lb*16 + cdl+i]
                 + bf2f((u16)(gr[qq] >> (16*i)));
        const float c = sigm(gv[1])*creg[i] + sigm(gv[0])*tanh_(gv[2]);
        creg[i] = c;
        const float h = sigm(gv[3])*tanh_(c);
        hp |= ((u32)f2bf(h)) << (16*i);
      }
      astore32(lstm + ((long)eb*S_ + tp)*D2_ + dir*H_ + col, hp);
    }
    gbar(flags, wg, dir*96, 96, ep0 + t + 1);
  }
  if (ew){ cst[eb*H_ + col] = creg[0]; cst[eb*H_ + col + 1] = creg[1]; }
}

// -------- persistent decode: 192 wgs = role(sub/word) x 2 bhalf x 48 slices ----
// Software-pipelined: role0 computes subword(t=r), role1 computes word(t=r-1),
// one grid barrier per round. Weights persistent in VGPRs (role1: 36 frags).
__global__ __launch_bounds__(512,2) void k_decode(
    const u16* __restrict__ Gsub, const u16* __restrict__ Wsub,
    const u16* __restrict__ Wwrd, const float* __restrict__ wbias,
    const float* __restrict__ clsW, const int* __restrict__ golds,
    u16* __restrict__ Sh0, u16* __restrict__ Sh1,
    u16* __restrict__ U0, u16* __restrict__ U1,
    float* __restrict__ scS, float* __restrict__ wcS, float* __restrict__ whS,
    float* __restrict__ partials, int* __restrict__ flags, int r0)
{
  __shared__ __align__(16) u16 lds[32*776];
  float* gbuf = (float*)lds;
  const int wg = blockIdx.x;
  const int role = wg / 96, rem = wg % 96, mh = rem / 48, s = rem % 48;
  const int tid = threadIdx.x;
  const int wave = tid >> 6, q = wave & 3, kh = wave >> 2;
  const int L = tid & 63, l16 = L & 15, quad = L >> 4;
  const int lb = tid >> 3, cdl = (tid & 7)*2;
  const int eb = mh*32 + lb, col = s*16 + cdl;
  const bool ew = (tid < 256);
  const int sr = tid >> 4, sl = tid & 15;

  bf16x8 wfr[36];
  float st0[2] = {0.f,0.f}, st1[2] = {0.f,0.f}, st2[2] = {0.f,0.f};
  if (role == 0){
    const u16* wr = Wsub + (long)(q*H_ + s*16 + l16)*H_ + kh*384 + quad*8;
    #pragma unroll
    for (int kk=0;kk<12;++kk) wfr[kk] = *(const bf16x8*)(wr + kk*32);
    if (ew){ st0[0] = scS[eb*H_+col]; st0[1] = scS[eb*H_+col+1]; }
  } else {
    const u16* wr = Wwrd + (long)(q*H_ + s*16 + l16)*2304 + kh*384 + quad*8;
    #pragma unroll
    for (int ch=0;ch<3;++ch)
      #pragma unroll
      for (int kk=0;kk<12;++kk)
        wfr[ch*12+kk] = *(const bf16x8*)(wr + ch*768 + kk*32);
    if (ew){ st1[0] = wcS[eb*H_+col]; st1[1] = wcS[eb*H_+col+1];
             st2[0] = whS[eb*H_+col]; st2[1] = whS[eb*H_+col+1]; }
  }

  for (int rr=0; rr<SEG; ++rr){
    const int r = r0 + rr;
    if (role == 0){
      if (r < 255){
        const int t = r;
        u16* ShR = (t&1) ? Sh1 : Sh0;
        u16* ShW = (t&1) ? Sh0 : Sh1;
        u16* Uw  = (t&1) ? U1  : U0;
        int gld = 0; u32 g0=0,g1=0,g2=0,g3=0;
        if (ew){
          gld = golds[eb*S_ + t + 1];
          const u16* grow = Gsub + ((long)eb*SEG + rr)*H4_ + col;
          g0 = *(const u32*)(grow);
          g1 = *(const u32*)(grow + H_);
          g2 = *(const u32*)(grow + 2*H_);
          g3 = *(const u32*)(grow + 3*H_);
        }
        {
          const u16* srow = ShR + (long)(mh*32 + sr)*H_;
          #pragma unroll
          for (int jj=0;jj<12;++jj){
            const int cu = (sl + jj*16)*4;
            *(u64*)&lds[sr*776 + cu] = aload64(srow + cu);
          }
        }
        __syncthreads();
        f32x4 acc[2];
        acc[0] = (f32x4){0.f,0.f,0.f,0.f}; acc[1] = acc[0];
        #pragma unroll
        for (int kk=0;kk<12;++kk)
          #pragma unroll
          for (int m=0;m<2;++m){
            bf16x8 a = *(const bf16x8*)&lds[(m*16+l16)*776 + kh*384 + kk*32 + quad*8];
            acc[m] = mfma16(a, wfr[kk], acc[m]);
          }
        __syncthreads();
        #pragma unroll
        for (int m=0;m<2;++m)
          #pragma unroll
          for (int r4=0;r4<4;++r4)
            gbuf[(q*2+kh)*512 + (m*16+quad*4+r4)*16 + l16] = acc[m][r4];
        __syncthreads();
        if (ew){
          const bool keep = (gld == 0);
          u32 gr[4] = {g0,g1,g2,g3};
          u32 hp=0, cp=0;
          #pragma unroll
          for (int i=0;i<2;++i){
            float gv[4];
            #pragma unroll
            for (int qq=0;qq<4;++qq)
              gv[qq] = gbuf[(qq*2+0)*512 + lb*16 + cdl+i]
                     + gbuf[(qq*2+1)*512 + lb*16 + cdl+i]
                     + bf2f((u16)(gr[qq] >> (16*i)));
            const float c1 = sigm(gv[1])*st0[i] + sigm(gv[0])*tanh_(gv[2]);
            const float h1 = sigm(gv[3])*tanh_(c1);
            st0[i] = keep ? c1 : 0.f;
            hp |= ((u32)f2bf(h1)) << (16*i);
            cp |= ((u32)f2bf(c1)) << (16*i);
          }
          astore32(Uw + (long)eb*2304 + col, hp);
          astore32(Uw + (long)eb*2304 + H_ + col, cp);
          astore32(ShW + (long)eb*H_ + col, keep ? hp : 0u);
        }
      }
    } else {
      if (r >= 1){
        const int tp = r - 1;
        const u16* Ur = (tp&1) ? U1 : U0;   // A wrote h1,c1 at round tp; our Wh(tp-1) is there too
        u16* Uw = (r&1) ? U1 : U0;          // Wh(tp) for round r+1 (shared w/ A's round-r writes)
        int gld = 0;
        if (ew) gld = golds[eb*S_ + r];     // = tp+1
        f32x4 acc[2];
        acc[0] = (f32x4){0.f,0.f,0.f,0.f}; acc[1] = acc[0];
        #pragma unroll
        for (int ch=0;ch<3;++ch){
          __syncthreads();
          {
            const u16* srow = Ur + (long)(mh*32 + sr)*2304 + ch*768;
            #pragma unroll
            for (int jj=0;jj<12;++jj){
              const int cu = (sl + jj*16)*4;
              *(u64*)&lds[sr*776 + cu] = aload64(srow + cu);
            }
          }
          __syncthreads();
          #pragma unroll
          for (int kk=0;kk<12;++kk)
            #pragma unroll
            for (int m=0;m<2;++m){
              bf16x8 a = *(const bf16x8*)&lds[(m*16+l16)*776 + kh*384 + kk*32 + quad*8];
              acc[m] = mfma16(a, wfr[ch*12+kk], acc[m]);
            }
        }
        __syncthreads();
        #pragma unroll
        for (int m=0;m<2;++m)
          #pragma unroll
          for (int r4=0;r4<4;++r4)
            gbuf[(q*2+kh)*512 + (m*16+quad*4+r4)*16 + l16] = acc[m][r4];
        __syncthreads();
        if (ew){
          const bool keep = (gld == 0);
          float p0 = 0.f, p1 = 0.f;
          u32 wp = 0;
          #pragma unroll
          for (int i=0;i<2;++i){
            float gv[4];
            #pragma unroll
            for (int qq=0;qq<4;++qq)
              gv[qq] = gbuf[(qq*2+0)*512 + lb*16 + cdl+i]
                     + gbuf[(qq*2+1)*512 + lb*16 + cdl+i]
                     + wbias[qq*H_ + col + i];
            const float wc1 = sigm(gv[1])*st1[i] + sigm(gv[0])*tanh_(gv[2]);
            const float wh1 = sigm(gv[3])*tanh_(wc1);
            st1[i] = keep ? st1[i] : wc1;
            st2[i] = keep ? st2[i] : wh1;
            p0 += wh1 * clsW[col + i];
            p1 += wh1 * clsW[2304 + col + i];
            wp |= ((u32)f2bf(st2[i])) << (16*i);
          }
          astore32(Uw + (long)eb*2304 + D2_ + col, wp);
          p0 += __shfl_xor(p0, 1); p0 += __shfl_xor(p0, 2); p0 += __shfl_xor(p0, 4);
          p1 += __shfl_xor(p1, 1); p1 += __shfl_xor(p1, 2); p1 += __shfl_xor(p1, 4);
          if ((tid & 7) == 0){
            float* pp = partials + ((long)(tp*48 + s)*64 + eb)*2;
            pp[0] = p0; pp[1] = p1;
          }
        }
      }
    }
    gbar(flags, wg, 0, 192, r0 + rr + 1);
  }
  if (ew){
    if (role == 0){
      scS[eb*H_+col] = st0[0]; scS[eb*H_+col+1] = st0[1];
    } else {
      wcS[eb*H_+col] = st1[0]; wcS[eb*H_+col+1] = st1[1];
      whS[eb*H_+col] = st2[0]; whS[eb*H_+col+1] = st2[1];
    }
  }
}

// ---------------- classifier epilogue: out = first | cls_b + wh-part + x-part --
__global__ __launch_bounds__(256) void k_cls(
    const u16* __restrict__ lstm, const float* __restrict__ partials,
    const float* __restrict__ clsW, const float* __restrict__ clsb,
    float* __restrict__ out)
{
  const int ts = blockIdx.x;
  const int b  = blockIdx.y;
  const int tid = threadIdx.x;
  if (ts == 0) {
    if (tid == 0) { out[(long)b*S_*2 + 0] = -1.f; out[(long)b*S_*2 + 1] = 1.f; }
    return;
  }
  const int t = ts - 1;
  float s0 = 0.f, s1 = 0.f;
  const u16* xr = lstm + ((long)b*S_ + ts)*D2_;
  for (int k = tid; k < D2_; k += 256) {
    const float xv = bf2f(xr[k]);
    s0 += xv * clsW[768 + k];
    s1 += xv * clsW[2304 + 768 + k];
  }
  if (tid < 48) {
    const float* pr = partials + ((long)(t*48 + tid)*64 + b)*2;
    s0 += pr[0]; s1 += pr[1];
  }
  __shared__ float r0[256], r1[256];
  r0[tid] = s0; r1[tid] = s1; __syncthreads();
  for (int off = 128; off > 0; off >>= 1) {
    if (tid < off) { r0[tid] += r0[tid+off]; r1[tid] += r1[tid+off]; }
    __syncthreads();
  }
  if (tid == 0) {
    out[((long)b*S_ + ts)*2 + 0] = r0[0] + clsb[0];
    out[((long)b*S_ + ts)*2 + 1] = r1[0] + clsb[1];
  }
}

extern "C" void kernel_launch(void* const* d_in, const int* in_sizes, int n_in,
                              void* d_out, int out_size, void* d_ws, size_t ws_size,
                              hipStream_t stream)
{
  (void)in_sizes; (void)n_in; (void)out_size; (void)ws_size;
  const float* x     = (const float*)d_in[0];
  const int*   golds = (const int*)d_in[1];
  const float* wihf  = (const float*)d_in[2];
  const float* whhf  = (const float*)d_in[3];
  const float* bfw   = (const float*)d_in[4];
  const float* wihb  = (const float*)d_in[5];
  const float* whhb  = (const float*)d_in[6];
  const float* bbw   = (const float*)d_in[7];
  const float* swih  = (const float*)d_in[8];
  const float* swhh  = (const float*)d_in[9];
  const float* sb    = (const float*)d_in[10];
  const float* wwih  = (const float*)d_in[11];
  const float* wwhh  = (const float*)d_in[12];
  const float* wb    = (const float*)d_in[13];
  const float* clsW  = (const float*)d_in[14];
  const float* clsb  = (const float*)d_in[15];
  float* out = (float*)d_out;

  char* base = (char*)d_ws;
  // -------- zero-init region (memset each launch) ------------------------------
  u16*   h0   = (u16*)(base + 0);            // 64x1536 bf16 zeros
  u16*   Sh0  = (u16*)(base + 196608);       // subword-h dbuf 64x768
  u16*   Sh1  = (u16*)(base + 294912);
  u16*   U0   = (u16*)(base + 393216);       // [h1|c1|Wh] dbuf 64x2304
  u16*   U1   = (u16*)(base + 688128);
  int*   flg2 = (int*)(base + 983040);       // 192 slots * 128 B
  int*   flg4 = (int*)(base + 1007616);
  float* cstf = (float*)(base + 1032192);    // bilstm fwd c-state 64x768 f32
  float* cstb = (float*)(base + 1228800);
  float* scS  = (float*)(base + 1425408);    // decode subword c
  float* wcS  = (float*)(base + 1622016);    // decode word c
  float* whS  = (float*)(base + 1818624);    // decode word h
  // zero region ends at 2,015,232
  // -------- scratch (fully written before read) --------------------------------
  u16* xb     = (u16*)(base + 2015232);
  u16* wihf_b = (u16*)(base + 27181056);
  u16* whhf_b = (u16*)(base + 31899648);
  u16* wihb_b = (u16*)(base + 36618240);
  u16* whhb_b = (u16*)(base + 41336832);
  u16* swih_b = (u16*)(base + 46055424);     // 3072x1536
  u16* swhh_b = (u16*)(base + 55492608);     // 3072x768
  u16* wwrd_b = (u16*)(base + 60211200);     // packed [word_Wih | word_Whh] 3072x2304
  u16* Gfseg  = (u16*)(base + 74366976);     // 4096x3072 bf16 segment
  u16* Gbseg  = (u16*)(base + 99532800);
  u16* lstm   = (u16*)(base + 124698624);    // (B,S,1536) bf16
  // total footprint: 175,030,272 B
  u16* Gsubseg = Gfseg;
  float* prt   = (float*)Gbseg;

  hipMemsetAsync(d_ws, 0, 2015232, stream);

  k_conv<<<16384, 256, 0, stream>>>(x,    xb,     768,  768,  768);
  k_conv<<<3072,  256, 0, stream>>>(wihf, wihf_b, 768,  768,  768);
  k_conv<<<3072,  256, 0, stream>>>(whhf, whhf_b, 768,  768,  768);
  k_conv<<<3072,  256, 0, stream>>>(wihb, wihb_b, 768,  768,  768);
  k_conv<<<3072,  256, 0, stream>>>(whhb, whhb_b, 768,  768,  768);
  k_conv<<<3072,  256, 0, stream>>>(swih, swih_b, 1536, 1536, 1536);
  k_conv<<<3072,  256, 0, stream>>>(swhh, swhh_b, 768,  768,  768);
  k_conv<<<3072,  256, 0, stream>>>(wwih, wwrd_b,        1536, 1536, 2304);
  k_conv<<<3072,  256, 0, stream>>>(wwhh, wwrd_b + 1536, 768,  768,  2304);

  dim3 gg(24, 32);
  for (int sgi = 0; sgi < 4; ++sgi) {
    const int t0f = sgi*SEG;
    const int tb0 = (3 - sgi)*SEG;
    k_gemm<<<gg, 256, 0, stream>>>(xb, wihf_b, bfw, Gfseg, 768, t0f);
    k_gemm<<<gg, 256, 0, stream>>>(xb, wihb_b, bbw, Gbseg, 768, tb0);
    k_bilstm<<<192, 512, 0, stream>>>(Gfseg, Gbseg, whhf_b, whhb_b, h0, lstm,
                                      cstf, cstb, flg2, t0f, tb0, sgi*SEG);
  }

  for (int sgi = 0; sgi < 4; ++sgi) {
    const int r0 = sgi*SEG;
    k_gemm<<<gg, 256, 0, stream>>>(lstm, swih_b, sb, Gsubseg, 1536, r0);
    k_decode<<<192, 512, 0, stream>>>(Gsubseg, swhh_b, wwrd_b, wb, clsW, golds,
                                      Sh0, Sh1, U0, U1, scS, wcS, whS, prt, flg4, r0);
  }

  dim3 gc(256, 64);
  k_cls<<<gc, 256, 0, stream>>>(lstm, prt, clsW, clsb, out);
}